// Round 9
// baseline (262.654 us; speedup 1.0000x reference)
//
#include <hip/hip_runtime.h>
#include <hip/hip_bf16.h>

// B=16, S=2048, D=128 causal attention, pre-scale threshold:
//   A = Q@T^T; A = (A>0.3 ? A : 0); causal -2^32; /sqrt(128); softmax; @V
// fp32 in/out, bf16 MFMA internal. Fixed-max softmax (m=0; post-threshold
// logits in [0,~9]) => partial (oacc, sum-l) accumulators are ADDITIVE.
//
// V9 = V8's verified 128-row 8-wave compute body + V7's verified barrier/dbuf
// pattern, at 2 blocks/CU (V8's fatal flaw was 1 block/CU: with a single
// block, every vmcnt+barrier stalls the whole CU -- no independent block to
// overlap the drain; all pipes measured <10% busy).
//  * LDS 80KB = dbuf tiles 64KB + single P 16KB; 2 x 80KB = 160KB/CU exactly.
//  * Grid 512 = b(16) x pair(8) x chunk(4) over the 34-tile light-first
//    enumeration [0,9,17,26,34)  => ~8.5 tiles/block, 2 blocks/CU, all
//    co-resident (spin-safe). Slots/CU = 17 (vs V7's 33): DMA bytes,
//    barriers, LDS ops per unit work all halved vs V7.
//  * At 104 VGPR, 2 blocks x 8 waves = 4 waves/SIMD is register-feasible
//    (416<=512) WITHOUT a launch-bounds cap (V3/V6's spill trap avoided).
//  * Combine: V5's proven chunk-static slots + release/acquire done counters;
//    bf16 partials (proven V5).

#define S_LEN 2048
#define D_DIM 128
#define THRESH 0.3f
#define SCALE 0.08838834764831845f   // 1/sqrt(128)

typedef __bf16 bf16x8 __attribute__((ext_vector_type(8)));
typedef __bf16 bf16x4 __attribute__((ext_vector_type(4)));
typedef float f32x4 __attribute__((ext_vector_type(4)));

#define GLD16(g, l)                                                         \
    __builtin_amdgcn_global_load_lds(                                       \
        (const __attribute__((address_space(1))) unsigned int*)(g),         \
        (__attribute__((address_space(3))) unsigned int*)(l), 16, 0, 0)

// ---- prep: Tb bf16 downcast; Vt[b][d][s] bf16 transpose; zero done ctrs ----
__global__ void prep_kernel(const float* __restrict__ V, const float* __restrict__ T,
                            __bf16* __restrict__ Vt, __bf16* __restrict__ Tb,
                            int* __restrict__ done) {
    __shared__ float tile[64][65];
    int bid = blockIdx.x;                      // 1024 blocks
    int tid = threadIdx.x;                     // 256 threads
    if (bid == 0) done[tid] = 0;               // zero 256 counters
    int b  = bid >> 6;
    int t2 = bid & 63;

    {   // T downcast: rows [t2*32, t2*32+32) of batch b; 16 f32 per thread
        int flat = tid * 16;
        int r = flat >> 7, cc = flat & 127;
        const float* p = T + ((size_t)b * S_LEN + t2 * 32 + r) * D_DIM + cc;
        __bf16* q = Tb + ((size_t)b * S_LEN + t2 * 32 + r) * D_DIM + cc;
        bf16x8 w0, w1;
        f32x4 a0 = *(const f32x4*)p,       a1 = *(const f32x4*)(p + 4);
        f32x4 a2 = *(const f32x4*)(p + 8), a3 = *(const f32x4*)(p + 12);
        #pragma unroll
        for (int j = 0; j < 4; ++j) {
            w0[j] = (__bf16)a0[j]; w0[4 + j] = (__bf16)a1[j];
            w1[j] = (__bf16)a2[j]; w1[4 + j] = (__bf16)a3[j];
        }
        *(bf16x8*)q = w0;
        *(bf16x8*)(q + 8) = w1;
    }

    int s0 = (t2 >> 1) * 64;
    int d0 = (t2 & 1) * 64;
    #pragma unroll
    for (int it = 0; it < 2; ++it) {
        int row = it * 32 + (tid >> 3);
        int c   = (tid & 7) * 8;
        const float* p = V + ((size_t)b * S_LEN + s0 + row) * D_DIM + d0 + c;
        *(f32x4*)(&tile[row][c])     = *(const f32x4*)p;
        *(f32x4*)(&tile[row][c + 4]) = *(const f32x4*)(p + 4);
    }
    __syncthreads();
    #pragma unroll
    for (int it = 0; it < 2; ++it) {
        int dr = it * 32 + (tid >> 3);
        int c  = (tid & 7) * 8;
        bf16x8 w;
        #pragma unroll
        for (int j = 0; j < 8; ++j) w[j] = (__bf16)tile[c + j][dr];
        *(bf16x8*)(Vt + ((size_t)b * D_DIM + d0 + dr) * S_LEN + s0 + c) = w;
    }
}

// ---------------- Flash attention, causal + threshold, fixed-max ----------------
// 512 threads = 8 waves, 128 q-rows per block. LDS 81920 B => 2 blocks/CU:
//   [    0, 32768)  Tt dbuf: 2 x (64 rows x 256B), XOR-swizzled via DMA source
//   [32768, 65536)  Vl dbuf: 2 x (128 rows x 128B), XOR-swizzled via DMA source
//   [65536, 81920)  P: [128 q][128B keys], swizzled; start doubles as
//                   Lx[8][64] f32 cross-wave l-reduction buffer between segs.
__global__ __launch_bounds__(512, 2)
void fa_kernel(const float* __restrict__ Q, const __bf16* __restrict__ Tb,
               const __bf16* __restrict__ Vt, float* __restrict__ O,
               __bf16* __restrict__ pO, float* __restrict__ pL,
               int* __restrict__ done) {
    __shared__ __align__(16) unsigned char smem[81920];

    const int bid = blockIdx.x;          // 512 = b(4b) | pair(3b) | chunk(2b)
    const int b   = bid & 15;
    const int pi  = (bid >> 4) & 7;      // pair: q-tiles (pi, 15-pi), 128 rows
    const int c   = bid >> 7;            // chunk 0..3 of [0,9,17,26,34)
    const int Lt  = 2 * pi + 2;          // light k-tile count (2..16)
    const int pr  = b * 8 + pi;
    const int jqL = pi, jqH = 15 - pi;

    const int tid  = threadIdx.x;
    const int lane = tid & 63;
    const int wv   = tid >> 6;           // 0..7
    const int col  = lane & 15;
    const int quad = lane >> 4;
    const int kg   = wv & 3;             // key-group (S) / d-group (PV)
    const int h    = wv >> 2;            // q-half

    unsigned char* Pb = smem + 65536;
    float* Lxf = (float*)(smem + 65536);

    const __bf16* TbB = Tb + (size_t)b * (S_LEN * D_DIM);
    const __bf16* VtB = Vt + (size_t)b * (D_DIM * S_LEN);

    // per-thread pre-swizzled global source offsets; 2 T + 2 V DMA per wave
    int toff[2], voff[2];
    #pragma unroll
    for (int i = 0; i < 2; ++i) {
        int trw = wv * 8 + i * 4 + quad;
        toff[i] = trw * 128 + (((lane & 15) ^ (trw & 7)) << 3);
        int drw = wv * 16 + i * 8 + (lane >> 3);
        voff[i] = drw * 2048 + (((lane & 7) ^ (drw & 7)) << 3);
    }

    auto issueTile = [&](int k0, int buf) {
        const __bf16* ts = TbB + (size_t)k0 * D_DIM;
        const __bf16* vs = VtB + k0;
        unsigned char* lt = smem + buf * 16384 + wv * 2048;
        unsigned char* lv = smem + 32768 + buf * 16384 + wv * 2048;
        GLD16(ts + toff[0], lt);
        GLD16(ts + toff[1], lt + 1024);
        GLD16(vs + voff[0], lv);
        GLD16(vs + voff[1], lv + 1024);
    };

    // Q as B-frags for the wave's 64 q-rows (q = 64h + 16t + col): 64 VGPRs
    bf16x8 qf[4][4];
    auto loadQ = [&](int jq) {
        #pragma unroll
        for (int t = 0; t < 4; ++t) {
            const float* qptr = Q + ((size_t)b * S_LEN + jq * 128 + h * 64 + 16 * t + col) * D_DIM + quad * 8;
            #pragma unroll
            for (int kk = 0; kk < 4; ++kk) {
                f32x4 a = *(const f32x4*)(qptr + kk * 32);
                f32x4 d = *(const f32x4*)(qptr + kk * 32 + 4);
                #pragma unroll
                for (int j = 0; j < 4; ++j) { qf[t][kk][j] = (__bf16)a[j]; qf[t][kk][4 + j] = (__bf16)d[j]; }
            }
        }
    };

    f32x4 oacc[4][2];     // [t][dn][r]: q = 64h+16t+quad*4+r, d = 32kg+16dn+col
    float lsum[4];        // per-lane partial l for q = 64h+16t+col (wave's 16 keys)
    float lfull[4][4];    // after finishSeg: full l for q = 64h+16t+quad*4+r

    auto computeTile = [&](unsigned char* Tt, unsigned char* Vl, int dKt) {
        // ---- S: wave's 16 keys (16kg..16kg+15) x its 64 q. A=T-frag, B=qf ----
        f32x4 sacc[4];
        #pragma unroll
        for (int t = 0; t < 4; ++t) sacc[t] = {0.f, 0.f, 0.f, 0.f};
        __builtin_amdgcn_s_setprio(1);
        #pragma unroll
        for (int kk = 0; kk < 4; ++kk) {
            int trow = kg * 16 + col;
            bf16x8 tf = *(const bf16x8*)(Tt + trow * 256 + ((kk * 64 + quad * 16) ^ ((trow & 7) << 4)));
            #pragma unroll
            for (int t = 0; t < 4; ++t)
                sacc[t] = __builtin_amdgcn_mfma_f32_16x16x32_bf16(tf, qf[t][kk], sacc[t], 0, 0, 0);
        }
        __builtin_amdgcn_s_setprio(0);

        // D[m = keyloc = 16kg+quad*4+r][n = q = 64h+16t+col]
        float p[4][4];
        #pragma unroll
        for (int t = 0; t < 4; ++t)
            #pragma unroll
            for (int r = 0; r < 4; ++r) {
                float s = sacc[t][r];
                float e = __expf(s * SCALE);
                p[t][r] = (s > THRESH) ? e : 1.0f;
            }
        if (dKt < 64) {                      // only the diag pair of tiles masks
            #pragma unroll
            for (int t = 0; t < 4; ++t)
                #pragma unroll
                for (int r = 0; r < 4; ++r)
                    if (kg * 16 + quad * 4 + r - (h * 64 + 16 * t + col) > dKt) p[t][r] = 0.0f;
        }
        #pragma unroll
        for (int t = 0; t < 4; ++t)
            lsum[t] += (p[t][0] + p[t][1]) + (p[t][2] + p[t][3]);

        // P[q][key]: key axis = r => one ds_write_b64 per t
        #pragma unroll
        for (int t = 0; t < 4; ++t) {
            int row = h * 64 + 16 * t + col;
            bf16x4 w = {(__bf16)p[t][0], (__bf16)p[t][1], (__bf16)p[t][2], (__bf16)p[t][3]};
            *(bf16x4*)(Pb + row * 128 + ((kg * 32 + quad * 8) ^ ((row & 7) << 4))) = w;
        }
        asm volatile("s_waitcnt lgkmcnt(0)" ::: "memory");  // P writes drained
        __builtin_amdgcn_s_barrier();                       // b2: P visible

        // ---- PV: wave's 32 d (32kg..) x its 64 q. A=P-frag, B=V-frag ----
        __builtin_amdgcn_s_setprio(1);
        #pragma unroll
        for (int kb = 0; kb < 2; ++kb) {
            bf16x8 pf[4];
            #pragma unroll
            for (int t = 0; t < 4; ++t) {
                int prow = h * 64 + 16 * t + col;
                pf[t] = *(const bf16x8*)(Pb + prow * 128 + ((kb * 64 + quad * 16) ^ ((prow & 7) << 4)));
            }
            #pragma unroll
            for (int dn = 0; dn < 2; ++dn) {
                int vrow = kg * 32 + 16 * dn + col;
                bf16x8 vf = *(const bf16x8*)(Vl + vrow * 128 + ((kb * 64 + quad * 16) ^ ((vrow & 7) << 4)));
                #pragma unroll
                for (int t = 0; t < 4; ++t)
                    oacc[t][dn] = __builtin_amdgcn_mfma_f32_16x16x32_bf16(pf[t], vf, oacc[t][dn], 0, 0, 0);
            }
        }
        __builtin_amdgcn_s_setprio(0);
    };

    auto runSeg = [&](int jq, int k0t, int nt) {
        loadQ(jq);
        #pragma unroll
        for (int t = 0; t < 4; ++t) {
            oacc[t][0] = {0.f, 0.f, 0.f, 0.f};
            oacc[t][1] = {0.f, 0.f, 0.f, 0.f};
            lsum[t] = 0.f;
        }
        issueTile(k0t * 64, 0);
        for (int s = 0; s < nt; ++s) {
            if (s + 1 < nt) {
                issueTile((k0t + s + 1) * 64, (s + 1) & 1);
                asm volatile("s_waitcnt vmcnt(4)" ::: "memory");  // tile s landed; s+1 in flight
            } else {
                asm volatile("s_waitcnt vmcnt(0)" ::: "memory");
            }
            __builtin_amdgcn_s_barrier();                         // b1: tile staged by all
            computeTile(smem + (s & 1) * 16384, smem + 32768 + (s & 1) * 16384,
                        128 * jq - 64 * (k0t + s));
            __builtin_amdgcn_s_barrier();                         // b3: slot done
        }
    };

    // cross-wave l reduction through Lx[8][64] (P region), once per segment
    auto finishSeg = [&]() {
        #pragma unroll
        for (int t = 0; t < 4; ++t) {
            float lw = lsum[t];
            lw += __shfl_xor(lw, 16);
            lw += __shfl_xor(lw, 32);      // sum over quads -> wave-l for q=64h+16t+col
            if (quad == 0) Lxf[wv * 64 + 16 * t + col] = lw;
        }
        __syncthreads();
        #pragma unroll
        for (int t = 0; t < 4; ++t)
            #pragma unroll
            for (int r = 0; r < 4; ++r) {
                int q16 = 16 * t + quad * 4 + r;   // within this wave's q-half
                lfull[t][r] = (Lxf[(4 * h + 0) * 64 + q16] + Lxf[(4 * h + 1) * 64 + q16]) +
                              (Lxf[(4 * h + 2) * 64 + q16] + Lxf[(4 * h + 3) * 64 + q16]);
            }
        __syncthreads();                   // Lx free before next seg's P writes
    };

    auto storeO = [&](int jq) {
        float* optr = O + ((size_t)b * S_LEN + jq * 128 + h * 64) * D_DIM + kg * 32;
        #pragma unroll
        for (int t = 0; t < 4; ++t)
            #pragma unroll
            for (int r = 0; r < 4; ++r) {
                float inv = 1.0f / lfull[t][r];
                #pragma unroll
                for (int dn = 0; dn < 2; ++dn)
                    optr[(16 * t + quad * 4 + r) * D_DIM + 16 * dn + col] = oacc[t][dn][r] * inv;
            }
    };

    auto storePartial = [&](int slot, int* dcnt) {
        __bf16* po = pO + (size_t)(pr * 4 + slot) * (128 * 128);
        float*  pl = pL + (size_t)(pr * 4 + slot) * 128;
        #pragma unroll
        for (int t = 0; t < 4; ++t)
            #pragma unroll
            for (int r = 0; r < 4; ++r)
                #pragma unroll
                for (int dn = 0; dn < 2; ++dn)
                    po[(h * 64 + 16 * t + quad * 4 + r) * 128 + kg * 32 + 16 * dn + col] = (__bf16)oacc[t][dn][r];
        if (kg == 0 && col == 0) {
            #pragma unroll
            for (int t = 0; t < 4; ++t)
                #pragma unroll
                for (int r = 0; r < 4; ++r)
                    pl[h * 64 + 16 * t + quad * 4 + r] = lfull[t][r];
        }
        __threadfence();
        __syncthreads();
        if (tid == 0)
            __hip_atomic_fetch_add(dcnt, 1, __ATOMIC_RELEASE, __HIP_MEMORY_SCOPE_AGENT);
    };

    auto addPartial = [&](int slot) {
        const __bf16* po = pO + (size_t)(pr * 4 + slot) * (128 * 128);
        const float*  pl = pL + (size_t)(pr * 4 + slot) * 128;
        #pragma unroll
        for (int t = 0; t < 4; ++t)
            #pragma unroll
            for (int r = 0; r < 4; ++r) {
                #pragma unroll
                for (int dn = 0; dn < 2; ++dn)
                    oacc[t][dn][r] += (float)po[(h * 64 + 16 * t + quad * 4 + r) * 128 + kg * 32 + 16 * dn + col];
                lfull[t][r] += pl[h * 64 + 16 * t + quad * 4 + r];
            }
    };

    auto spinFor = [&](int* dcnt, int need) {
        if (tid == 0) {
            while (__hip_atomic_load(dcnt, __ATOMIC_ACQUIRE, __HIP_MEMORY_SCOPE_AGENT) < need)
                __builtin_amdgcn_s_sleep(8);
        }
        __syncthreads();
        __threadfence();
    };

    // ---- chunk schedule over the 34-tile pair enumeration [0,9,17,26,34) ----
    // light = positions [0,Lt), heavy = [Lt,34). Lt<=9 <=> pi<=3.
    if (c == 0) {
        if (Lt <= 9) {
            runSeg(jqL, 0, Lt);                  // light, complete
            finishSeg();
            storeO(jqL);
            runSeg(jqH, 0, 9 - Lt);              // heavy prefix (>=1 tile)
            finishSeg();
            storePartial(0, &done[pr]);
        } else {
            runSeg(jqL, 0, 9);                   // light part 1 of 2
            finishSeg();
            storePartial(3, &done[128 + pr]);
        }
    } else if (c == 1) {
        if (Lt <= 9) {
            runSeg(jqH, 9 - Lt, 8);
            finishSeg();
            storePartial(1, &done[pr]);
        } else {
            runSeg(jqH, 0, 17 - Lt);             // heavy first (lets c0 finish light p1)
            finishSeg();
            storePartial(1, &done[pr]);
            runSeg(jqL, 9, Lt - 9);              // light part 2 + finalize
            finishSeg();
            spinFor(&done[128 + pr], 1);
            addPartial(3);
            storeO(jqL);
        }
    } else if (c == 2) {
        runSeg(jqH, 17 - Lt, 9);
        finishSeg();
        storePartial(2, &done[pr]);
    } else {
        runSeg(jqH, 26 - Lt, 8);                 // heavy tail incl. diag pair
        finishSeg();
        int s0 = (Lt <= 9) ? 0 : 1;
        spinFor(&done[pr], 3 - s0);
        for (int s = s0; s < 3; ++s) addPartial(s);
        storeO(jqH);
    }
}

extern "C" void kernel_launch(void* const* d_in, const int* in_sizes, int n_in,
                              void* d_out, int out_size, void* d_ws, size_t ws_size,
                              hipStream_t stream) {
    const float* Q = (const float*)d_in[0];
    const float* T = (const float*)d_in[1];
    const float* V = (const float*)d_in[2];
    float* O = (float*)d_out;

    // ws: Vt 8MB | Tb 8MB | pO 16MB bf16 (128 pairs x 4 slots x 128x128)
    //   | pL 256KB | done 1KB   (~32.3MB)
    unsigned char* ws = (unsigned char*)d_ws;
    __bf16* Vt = (__bf16*)ws;
    __bf16* Tb = (__bf16*)(ws + 8388608);
    __bf16* pO = (__bf16*)(ws + 16777216);
    float*  pL = (float*)(ws + 16777216 + 16777216);
    int*  done = (int*)(ws + 16777216 + 16777216 + 262144);

    prep_kernel<<<1024, 256, 0, stream>>>(V, T, Vt, Tb, done);
    fa_kernel<<<512, 512, 0, stream>>>(Q, Tb, Vt, O, pO, pL, done);
}

// Round 10
// 144.750 us; speedup vs baseline: 1.8145x; 1.8145x over previous
//
#include <hip/hip_runtime.h>
#include <hip/hip_bf16.h>

// B=16, S=2048, D=128 causal attention, pre-scale threshold:
//   A = Q@T^T; A = (A>0.3 ? A : 0); causal -2^32; /sqrt(128); softmax; @V
// fp32 in/out, bf16 MFMA internal. Fixed-max softmax (m=0; post-threshold
// logits in [0,~9]) => partial (oacc, sum-l) accumulators are ADDITIVE.
//
// V10 = V7's verified 4-wave compute body (44us, 104 VGPR: QK^T key-split,
// PV d-split, shared-P with one mid-slot barrier) with block-TLP x4:
//  * LDS 40KB: SINGLE-buffered tiles (16K Tt + 16K Vl) + 8K P => 4 blocks/CU
//    capacity (V9 proved 8-wave lockstep + exact-fit 80KBx2 fails; V2/V8/V9
//    all show 8-wave blocks are structurally slow. 4-wave + multi-block is
//    the only fast regime measured: V4 46.8, V7 44).
//  * Grid 1024 = b(16) x pair(16) x chunk(4) over the 33-tile light-first
//    enumeration [0,9,17,25,33). DMA issued after the read-done barrier;
//    the exposed HBM/L2 latency is hidden by the other 3 resident blocks.
//  * Zero cross-block sync: <=5 static bf16 partial slots per pair
//    (heavy -> slot=chunk 0..3; light 2-chunk case -> slots 0,4; light sole
//    contributor stores O directly); nrm kernel sums slots. No spins/ctrs.
//  * b-in-low-bits block order => all blocks of batch b land on XCD b%8:
//    each XCD's L2 sees only 2 batches' T/V (4MB, L2-fits).

#define S_LEN 2048
#define D_DIM 128
#define THRESH 0.3f
#define SCALE 0.08838834764831845f   // 1/sqrt(128)

typedef __bf16 bf16x8 __attribute__((ext_vector_type(8)));
typedef __bf16 bf16x4 __attribute__((ext_vector_type(4)));
typedef float f32x4 __attribute__((ext_vector_type(4)));

#define GLD16(g, l)                                                         \
    __builtin_amdgcn_global_load_lds(                                       \
        (const __attribute__((address_space(1))) unsigned int*)(g),         \
        (__attribute__((address_space(3))) unsigned int*)(l), 16, 0, 0)

// ---- prep: Tb bf16 downcast; Vt[b][d][s] bf16 transpose ----
__global__ void prep_kernel(const float* __restrict__ V, const float* __restrict__ T,
                            __bf16* __restrict__ Vt, __bf16* __restrict__ Tb) {
    __shared__ float tile[64][65];
    int bid = blockIdx.x;                      // 1024 blocks
    int tid = threadIdx.x;                     // 256 threads
    int b  = bid >> 6;
    int t2 = bid & 63;

    {   // T downcast: rows [t2*32, t2*32+32) of batch b; 16 f32 per thread
        int flat = tid * 16;
        int r = flat >> 7, cc = flat & 127;
        const float* p = T + ((size_t)b * S_LEN + t2 * 32 + r) * D_DIM + cc;
        __bf16* q = Tb + ((size_t)b * S_LEN + t2 * 32 + r) * D_DIM + cc;
        bf16x8 w0, w1;
        f32x4 a0 = *(const f32x4*)p,       a1 = *(const f32x4*)(p + 4);
        f32x4 a2 = *(const f32x4*)(p + 8), a3 = *(const f32x4*)(p + 12);
        #pragma unroll
        for (int j = 0; j < 4; ++j) {
            w0[j] = (__bf16)a0[j]; w0[4 + j] = (__bf16)a1[j];
            w1[j] = (__bf16)a2[j]; w1[4 + j] = (__bf16)a3[j];
        }
        *(bf16x8*)q = w0;
        *(bf16x8*)(q + 8) = w1;
    }

    int s0 = (t2 >> 1) * 64;
    int d0 = (t2 & 1) * 64;
    #pragma unroll
    for (int it = 0; it < 2; ++it) {
        int row = it * 32 + (tid >> 3);
        int c   = (tid & 7) * 8;
        const float* p = V + ((size_t)b * S_LEN + s0 + row) * D_DIM + d0 + c;
        *(f32x4*)(&tile[row][c])     = *(const f32x4*)p;
        *(f32x4*)(&tile[row][c + 4]) = *(const f32x4*)(p + 4);
    }
    __syncthreads();
    #pragma unroll
    for (int it = 0; it < 2; ++it) {
        int dr = it * 32 + (tid >> 3);
        int c  = (tid & 7) * 8;
        bf16x8 w;
        #pragma unroll
        for (int j = 0; j < 8; ++j) w[j] = (__bf16)tile[c + j][dr];
        *(bf16x8*)(Vt + ((size_t)b * D_DIM + d0 + dr) * S_LEN + s0 + c) = w;
    }
}

// ---------------- Flash attention, causal + threshold, fixed-max ----------------
// 256 threads = 4 waves, 64 q-rows per block. LDS 40960 B => 4 blocks/CU:
//   [    0, 16384)  Tt: 64 keys x 256B, XOR-swizzled via DMA source
//   [16384, 32768)  Vl: 128 d x 128B, XOR-swizzled via DMA source
//   [32768, 40960)  P: [64 q][128B keys] swizzled; start doubles as Lx[4][64].
__global__ __launch_bounds__(256, 2)
void fa_kernel(const float* __restrict__ Q, const __bf16* __restrict__ Tb,
               const __bf16* __restrict__ Vt, float* __restrict__ O,
               __bf16* __restrict__ pO, float* __restrict__ pL) {
    __shared__ __align__(16) unsigned char smem[40960];

    const int bid = blockIdx.x;          // 1024 = b(4b) | pair(4b) | chunk(2b)
    const int b   = bid & 15;
    const int pi  = (bid >> 4) & 15;     // pair: 64-row q-tiles (pi, 31-pi)
    const int c   = bid >> 8;            // chunk 0..3 of [0,9,17,25,33)
    const int Lt  = pi + 1;              // light k-tile count (1..16)
    const int pr  = b * 16 + pi;
    const int jqL = pi, jqH = 31 - pi;

    const int tid  = threadIdx.x;
    const int lane = tid & 63;
    const int wv   = tid >> 6;
    const int col  = lane & 15;
    const int quad = lane >> 4;

    unsigned char* Pb = smem + 32768;
    float* Lxf = (float*)(smem + 32768);

    const __bf16* TbB = Tb + (size_t)b * (S_LEN * D_DIM);
    const __bf16* VtB = Vt + (size_t)b * (D_DIM * S_LEN);

    // per-thread pre-swizzled global source offsets for the 4+4 DMA issues
    int toff[4], voff[4];
    #pragma unroll
    for (int i = 0; i < 4; ++i) {
        int trw = wv * 16 + i * 4 + (lane >> 4);
        toff[i] = trw * 128 + (((lane & 15) ^ (trw & 7)) << 3);
        int drw = wv * 32 + i * 8 + (lane >> 3);
        voff[i] = drw * 2048 + (((lane & 7) ^ (drw & 7)) << 3);
    }

    auto issueTile = [&](int k0) {
        const __bf16* ts = TbB + (size_t)k0 * D_DIM;
        const __bf16* vs = VtB + k0;
        unsigned char* lt = smem + wv * 4096;
        unsigned char* lv = smem + 16384 + wv * 4096;
        #pragma unroll
        for (int i = 0; i < 4; ++i) GLD16(ts + toff[i], lt + i * 1024);
        #pragma unroll
        for (int i = 0; i < 4; ++i) GLD16(vs + voff[i], lv + i * 1024);
    };

    // Q as PERSISTENT B-frags for all 64 q-rows: qf[t][kk] holds
    // Q[q = 16t+col][k = kk*32 + quad*8 + j]   (64 VGPRs)
    bf16x8 qf[4][4];
    auto loadQ = [&](int jq) {
        #pragma unroll
        for (int t = 0; t < 4; ++t) {
            const float* qptr = Q + ((size_t)b * S_LEN + jq * 64 + 16 * t + col) * D_DIM + quad * 8;
            #pragma unroll
            for (int kk = 0; kk < 4; ++kk) {
                f32x4 a = *(const f32x4*)(qptr + kk * 32);
                f32x4 d = *(const f32x4*)(qptr + kk * 32 + 4);
                #pragma unroll
                for (int j = 0; j < 4; ++j) { qf[t][kk][j] = (__bf16)a[j]; qf[t][kk][4 + j] = (__bf16)d[j]; }
            }
        }
    };

    f32x4 oacc[4][2];     // [t][dn][r]: q = 16t+quad*4+r, d = 32wv+16dn+col
    float lsum[4];        // per-lane l partial for q = 16t+col (this wave's keys)
    float lfull[4][4];    // after finishSeg: full l for q = 16t+quad*4+r

    auto computeTile = [&](bool diag) {
        unsigned char* Tt = smem;
        unsigned char* Vl = smem + 16384;

        // ---- S: wave's 16 keys x all 64 q.  A = T-frag, B = qf. ----
        f32x4 sacc[4];
        #pragma unroll
        for (int t = 0; t < 4; ++t) sacc[t] = {0.f, 0.f, 0.f, 0.f};
        __builtin_amdgcn_s_setprio(1);
        #pragma unroll
        for (int kk = 0; kk < 4; ++kk) {
            int trow = wv * 16 + col;      // key = 16wv + col  (A-frag m=col)
            bf16x8 tf = *(const bf16x8*)(Tt + trow * 256 + ((kk * 64 + quad * 16) ^ ((trow & 7) << 4)));
            #pragma unroll
            for (int t = 0; t < 4; ++t)
                sacc[t] = __builtin_amdgcn_mfma_f32_16x16x32_bf16(tf, qf[t][kk], sacc[t], 0, 0, 0);
        }
        __builtin_amdgcn_s_setprio(0);

        // D[m = key = quad*4+r (+16wv)][n = q = col (+16t)]
        float p[4][4];
        #pragma unroll
        for (int t = 0; t < 4; ++t)
            #pragma unroll
            for (int r = 0; r < 4; ++r) {
                float s = sacc[t][r];
                float e = __expf(s * SCALE);
                p[t][r] = (s > THRESH) ? e : 1.0f;
            }
        if (diag) {
            #pragma unroll
            for (int t = 0; t < 4; ++t)
                #pragma unroll
                for (int r = 0; r < 4; ++r)
                    if (wv * 16 + quad * 4 + r > 16 * t + col) p[t][r] = 0.0f;
        }
        #pragma unroll
        for (int t = 0; t < 4; ++t)
            lsum[t] += (p[t][0] + p[t][1]) + (p[t][2] + p[t][3]);

        // P[q][key]: key axis = r => 4 contiguous bf16 = one ds_write_b64
        #pragma unroll
        for (int t = 0; t < 4; ++t) {
            int row = 16 * t + col;
            bf16x4 w = {(__bf16)p[t][0], (__bf16)p[t][1], (__bf16)p[t][2], (__bf16)p[t][3]};
            *(bf16x4*)(Pb + row * 128 + ((32 * wv + 8 * quad) ^ ((row & 7) << 4))) = w;
        }
        asm volatile("s_waitcnt lgkmcnt(0)" ::: "memory");  // P writes drained
        __builtin_amdgcn_s_barrier();                       // b2: P visible

        // ---- PV: wave's 32 d-cols x all 64 q.  A = P-frag, B = V-frag. ----
        __builtin_amdgcn_s_setprio(1);
        #pragma unroll
        for (int kb = 0; kb < 2; ++kb) {
            bf16x8 pf[4];
            #pragma unroll
            for (int t = 0; t < 4; ++t) {
                int prow = 16 * t + col;
                pf[t] = *(const bf16x8*)(Pb + prow * 128 + ((kb * 64 + quad * 16) ^ ((prow & 7) << 4)));
            }
            #pragma unroll
            for (int dn = 0; dn < 2; ++dn) {
                int vrow = 32 * wv + 16 * dn + col;
                bf16x8 vf = *(const bf16x8*)(Vl + vrow * 128 + ((kb * 64 + quad * 16) ^ ((vrow & 7) << 4)));
                #pragma unroll
                for (int t = 0; t < 4; ++t)
                    oacc[t][dn] = __builtin_amdgcn_mfma_f32_16x16x32_bf16(pf[t], vf, oacc[t][dn], 0, 0, 0);
            }
        }
        __builtin_amdgcn_s_setprio(0);
    };

    auto runSeg = [&](int jq, int k0t, int nt) {
        loadQ(jq);
        #pragma unroll
        for (int t = 0; t < 4; ++t) {
            oacc[t][0] = {0.f, 0.f, 0.f, 0.f};
            oacc[t][1] = {0.f, 0.f, 0.f, 0.f};
            lsum[t] = 0.f;
        }
        issueTile(k0t * 64);
        for (int s = 0; s < nt; ++s) {
            asm volatile("s_waitcnt vmcnt(0)" ::: "memory");  // tile s landed (this wave)
            __builtin_amdgcn_s_barrier();                     // b1: all waves' DMA landed
            computeTile(k0t + s == jq);
            __builtin_amdgcn_s_barrier();                     // b3: all reads of tile done
            if (s + 1 < nt) issueTile((k0t + s + 1) * 64);    // overwrite is now safe
        }
    };

    // cross-wave l reduction (once per segment) through Lx[4][64] (P region)
    auto finishSeg = [&]() {
        #pragma unroll
        for (int t = 0; t < 4; ++t) {
            float lw = lsum[t];
            lw += __shfl_xor(lw, 16);
            lw += __shfl_xor(lw, 32);          // sum over quads: wave-partial l[q=16t+col]
            if (quad == 0) Lxf[wv * 64 + 16 * t + col] = lw;
        }
        __syncthreads();
        #pragma unroll
        for (int t = 0; t < 4; ++t)
            #pragma unroll
            for (int r = 0; r < 4; ++r) {
                int q = 16 * t + quad * 4 + r;
                lfull[t][r] = (Lxf[q] + Lxf[64 + q]) + (Lxf[128 + q] + Lxf[192 + q]);
            }
        __syncthreads();                        // Lx free before next seg's P writes
    };

    auto storeO = [&](int jq) {
        float* optr = O + ((size_t)b * S_LEN + jq * 64) * D_DIM;
        #pragma unroll
        for (int t = 0; t < 4; ++t)
            #pragma unroll
            for (int r = 0; r < 4; ++r) {
                float inv = 1.0f / lfull[t][r];
                #pragma unroll
                for (int dn = 0; dn < 2; ++dn)
                    optr[(16 * t + quad * 4 + r) * D_DIM + 32 * wv + 16 * dn + col] = oacc[t][dn][r] * inv;
            }
    };

    auto storePartial = [&](int slot) {
        __bf16* po = pO + (size_t)(pr * 5 + slot) * (64 * 128);
        float*  pl = pL + (size_t)(pr * 5 + slot) * 64;
        #pragma unroll
        for (int t = 0; t < 4; ++t)
            #pragma unroll
            for (int r = 0; r < 4; ++r)
                #pragma unroll
                for (int dn = 0; dn < 2; ++dn)
                    po[(16 * t + quad * 4 + r) * 128 + 32 * wv + 16 * dn + col] = (__bf16)oacc[t][dn][r];
        if (wv == 0 && col == 0) {
            #pragma unroll
            for (int t = 0; t < 4; ++t)
                #pragma unroll
                for (int r = 0; r < 4; ++r)
                    pl[16 * t + quad * 4 + r] = lfull[t][r];
        }
    };

    // ---- chunk schedule over the 33-tile enumeration [0,9,17,25,33) ----
    // light = positions [0,Lt), heavy = [Lt,33).
    const int Btab[5] = {0, 9, 17, 25, 33};
    const int lo = Btab[c], hi = Btab[c + 1];

    int lend = Lt < hi ? Lt : hi;
    if (lo < lend) {                            // light segment (c==0 or c==1)
        runSeg(jqL, lo, lend - lo);
        finishSeg();
        if (Lt <= 9)      storeO(jqL);          // sole contributor (c==0)
        else if (c == 0)  storePartial(0);      // light part 1 (heavy unused slot 0)
        else              storePartial(4);      // light part 2 (c==1)
    }
    int hstart = Lt > lo ? Lt : lo;
    if (hstart < hi) {                          // heavy segment
        runSeg(jqH, hstart - Lt, hi - hstart);
        finishSeg();
        storePartial(c);
    }
}

// ---- nrm: sum partial slots, normalize, store ----
// grid 1024 = b(4b) | pi(4b) | tile(1b) | half(1b); 256 thr, 16 f32/thread.
__global__ void nrm_kernel(const __bf16* __restrict__ pO, const float* __restrict__ pL,
                           float* __restrict__ O) {
    int bid  = blockIdx.x;
    int half = bid & 1;
    int tile = (bid >> 1) & 1;
    int pi   = (bid >> 2) & 15;
    int b    = bid >> 6;
    int Lt   = pi + 1;
    int tid  = threadIdx.x;
    int row  = half * 32 + (tid >> 3);
    int cc   = (tid & 7) * 16;
    int pr   = b * 16 + pi;

    float acc[16];
    #pragma unroll
    for (int j = 0; j < 16; ++j) acc[j] = 0.f;
    float l = 0.f;

    auto addSlot = [&](int slot) {
        const __bf16* po = pO + (size_t)(pr * 5 + slot) * (64 * 128) + row * 128 + cc;
        bf16x8 a = *(const bf16x8*)po;
        bf16x8 d = *(const bf16x8*)(po + 8);
        #pragma unroll
        for (int j = 0; j < 8; ++j) { acc[j] += (float)a[j]; acc[8 + j] += (float)d[j]; }
        l += pL[(pr * 5 + slot) * 64 + row];
    };

    int qt;
    if (tile == 1) {                 // heavy: slots {0..3} if Lt<9 else {1,2,3}
        qt = 31 - pi;
        for (int s = (Lt < 9) ? 0 : 1; s < 4; ++s) addSlot(s);
    } else {                         // light: only the 2-contributor case
        if (Lt <= 9) return;         // sole contributor stored directly in fa
        qt = pi;
        addSlot(0); addSlot(4);
    }
    float inv = 1.0f / l;
    float* op = O + ((size_t)b * S_LEN + qt * 64 + row) * D_DIM + cc;
    #pragma unroll
    for (int j = 0; j < 4; ++j) {
        f32x4 o;
        #pragma unroll
        for (int r = 0; r < 4; ++r) o[r] = acc[j * 4 + r] * inv;
        *(f32x4*)(op + j * 4) = o;
    }
}

extern "C" void kernel_launch(void* const* d_in, const int* in_sizes, int n_in,
                              void* d_out, int out_size, void* d_ws, size_t ws_size,
                              hipStream_t stream) {
    const float* Q = (const float*)d_in[0];
    const float* T = (const float*)d_in[1];
    const float* V = (const float*)d_in[2];
    float* O = (float*)d_out;

    // ws: Vt 8MB | Tb 8MB | pO 21MB bf16 (256 pairs x 5 slots x 64x128)
    //   | pL 320KB   (~37.3MB)
    unsigned char* ws = (unsigned char*)d_ws;
    __bf16* Vt = (__bf16*)ws;
    __bf16* Tb = (__bf16*)(ws + 8388608);
    __bf16* pO = (__bf16*)(ws + 16777216);
    float*  pL = (float*)(ws + 16777216 + 20971520);

    prep_kernel<<<1024, 256, 0, stream>>>(V, T, Vt, Tb);
    fa_kernel<<<1024, 256, 0, stream>>>(Q, Tb, Vt, O, pO, pL);
    nrm_kernel<<<1024, 256, 0, stream>>>(pO, pL, O);
}